// Round 10
// baseline (182.907 us; speedup 1.0000x reference)
//
#include <hip/hip_runtime.h>
#include <hip/hip_bf16.h>
#include <stdint.h>

typedef __attribute__((ext_vector_type(4))) int i32x4;

#define GLOAD(g, l) __builtin_amdgcn_global_load_lds(                      \
    (const __attribute__((address_space(1))) void*)(g),                    \
    (__attribute__((address_space(3))) void*)(l), 16, 0, 0)

#define MFMAI8 __builtin_amdgcn_mfma_i32_16x16x64_i8
#define BARRIER __builtin_amdgcn_s_barrier

// ---- W -> sign(W) as i8 {-1,0,1}, plus per-block partial sums of |W| ----
__global__ __launch_bounds__(256) void wsign_kernel(
    const float* __restrict__ W, char* __restrict__ S,
    float* __restrict__ partials) {
  const int tid = threadIdx.x;
  const int idx = blockIdx.x * 256 + tid;  // one int4 (16 f32 -> 16 i8) each
  const float4* wp = reinterpret_cast<const float4*>(W) + (size_t)idx * 4;
  float s = 0.f;
  int out[4];
#pragma unroll
  for (int i = 0; i < 4; ++i) {
    float4 w = wp[i];
    int b0 = (w.x > 0.f) - (w.x < 0.f);
    int b1 = (w.y > 0.f) - (w.y < 0.f);
    int b2 = (w.z > 0.f) - (w.z < 0.f);
    int b3 = (w.w > 0.f) - (w.w < 0.f);
    out[i] = (b0 & 255) | ((b1 & 255) << 8) | ((b2 & 255) << 16) |
             ((b3 & 255) << 24);
    s += fabsf(w.x) + fabsf(w.y) + fabsf(w.z) + fabsf(w.w);
  }
  reinterpret_cast<int4*>(S)[idx] =
      make_int4(out[0], out[1], out[2], out[3]);
#pragma unroll
  for (int off = 32; off > 0; off >>= 1) s += __shfl_down(s, off, 64);
  __shared__ float sm[4];
  if ((tid & 63) == 0) sm[tid >> 6] = s;
  __syncthreads();
  if (tid == 0) partials[blockIdx.x] = sm[0] + sm[1] + sm[2] + sm[3];
}

// ---- x f32 -> i8 per-row quantization; qrow = amax/127 ------------------
__global__ __launch_bounds__(256) void xquant_kernel(
    const float* __restrict__ X, char* __restrict__ XQ,
    float* __restrict__ qrow) {
  const int row = blockIdx.x;
  const int tid = threadIdx.x;
  const float4* xr = reinterpret_cast<const float4*>(X + (size_t)row * 4096);
  float4 v[4];
  float am = 0.f;
#pragma unroll
  for (int i = 0; i < 4; ++i) {
    v[i] = xr[tid * 4 + i];
    am = fmaxf(am, fmaxf(fmaxf(fabsf(v[i].x), fabsf(v[i].y)),
                         fmaxf(fabsf(v[i].z), fabsf(v[i].w))));
  }
#pragma unroll
  for (int off = 1; off < 64; off <<= 1)
    am = fmaxf(am, __shfl_xor(am, off, 64));
  __shared__ float wm[4];
  if ((tid & 63) == 0) wm[tid >> 6] = am;
  __syncthreads();
  float amax = fmaxf(fmaxf(wm[0], wm[1]), fmaxf(wm[2], wm[3]));
  amax = fmaxf(amax, 1e-20f);
  const float rq = 127.f / amax;
  int out[4];
#pragma unroll
  for (int i = 0; i < 4; ++i) {
    int b0 = __float2int_rn(v[i].x * rq);
    int b1 = __float2int_rn(v[i].y * rq);
    int b2 = __float2int_rn(v[i].z * rq);
    int b3 = __float2int_rn(v[i].w * rq);
    out[i] = (b0 & 255) | ((b1 & 255) << 8) | ((b2 & 255) << 16) |
             ((b3 & 255) << 24);
  }
  reinterpret_cast<int4*>(XQ + (size_t)row * 4096)[tid] =
      make_int4(out[0], out[1], out[2], out[3]);
  if (tid == 0) qrow[row] = amax * (1.f / 127.f);
}

// ---- deterministic reduce of partials -> scale = mean(|W|) --------------
__global__ __launch_bounds__(256) void finalize_kernel(
    const float* __restrict__ partials, float* __restrict__ scale) {
  const int tid = threadIdx.x;
  float s = 0.f;
  for (int i = tid; i < 4096; i += 256) s += partials[i];
#pragma unroll
  for (int off = 32; off > 0; off >>= 1) s += __shfl_down(s, off, 64);
  __shared__ float sm[4];
  if ((tid & 63) == 0) sm[tid >> 6] = s;
  __syncthreads();
  if (tid == 0) scale[0] = (sm[0] + sm[1] + sm[2] + sm[3]) * (1.0f / 16777216.0f);
}

// ---- 256x256x128 8-wave i8 GEMM, free-run region + 2 barriers/K-step ----
// Per K-step t (par=t&1):
//   [stage A(t+1) -> A slots par^1]                (safe: 2 barriers since
//                                                   last reads of those slots)
//   RD_B; {RD_A(q); MFMA(q)} x4                    (NO manual lgkm; compiler
//                                                   emits counted lgkmcnt and
//                                                   pipelines quadrants)
//   BARRIER            -- all waves' reads of parity-par slots complete
//   [stage B(t+2) -> B slots par]                  (slots just freed)
//   vmcnt(4) gate      -- FIFO: [B(t+1):4, A(t+1):4, B(t+2):4] -> drains
//                          exactly step t+1; vmcnt(0) when t+2>=NT
//   BARRIER            -- residency block-wide
// Slots (16 KiB): A par0=0,1  A par1=2,3  B par0=4,5  B par1=6,7.
__global__ __launch_bounds__(512, 2) void gemm_i8_kernel(
    const char* __restrict__ A,  // [8192][4096] i8
    const char* __restrict__ B,  // [4096][4096] i8 sign
    const float* __restrict__ scale_p, const float* __restrict__ qrow,
    float* __restrict__ C) {
  constexpr int M = 8192, N = 4096, K = 4096;
  constexpr int NT = K / 128;  // 32 K-steps
  __shared__ __align__(16) char lds[131072];  // 8 slots x 16 KiB

  const int tid = threadIdx.x;
  const int wid = tid >> 6;
  const int lane = tid & 63;
  const int wr = wid >> 2;            // 0..1 : A half (M-rows)
  const int wc = wid & 3;             // 0..3 : 64-col group
  const int bh = wc >> 1;             // B half slot
  const int bsub = (wc & 1) * 8192;   // 64-row band within B half (bytes)
  const int fr = lane & 15;
  const int fq = lane >> 4;
  // swizzled 16B-slot byte offsets, kk = 0,1 (k = kk*64 + fq*16 + j)
  const int sk0 = ((fq) ^ (fr & 7)) * 16;
  const int sk1 = ((4 + fq) ^ (fr & 7)) * 16;

  // XCD-aware swizzle; nwg = 512, divisible by 8
  const int bid = blockIdx.x;
  const int swz = (bid & 7) * 64 + (bid >> 3);
  const int tm = swz >> 4, tn = swz & 15;

  // staging sources (per-thread, pre-inverse-swizzled); 16B granules
  const int srow = tid >> 3;
  const int sg = (tid & 7) ^ (srow & 7);
  const char* aSrc0 = A + (size_t)(tm * 256 + srow) * K + sg * 16;
  const char* aSrc1 = aSrc0 + (size_t)128 * K;
  const char* bSrc0 = B + (size_t)(tn * 256 + srow) * K + sg * 16;
  const char* bSrc1 = bSrc0 + (size_t)128 * K;

#define STAGE(srcBase, slotIdx, koff)                              \
  do {                                                             \
    const char* _s = (srcBase) + (koff);                           \
    char* _d = lds + (slotIdx) * 16384 + wid * 1024;               \
    GLOAD(_s, _d);                                                 \
    GLOAD(_s + (size_t)64 * K, _d + 8192);                         \
  } while (0)

  // fragment read bases; parity p adds p*32768
  const char* aSp0 = lds + wr * 16384 + fr * 128;
  const char* bSp0 = lds + 65536 + bh * 16384 + bsub + fr * 128;

  i32x4 acc[8][4];
#pragma unroll
  for (int m = 0; m < 8; ++m)
#pragma unroll
    for (int n = 0; n < 4; ++n) acc[m][n] = (i32x4){0, 0, 0, 0};

#define RD_B(bS)                                                       \
  _Pragma("unroll") for (int n = 0; n < 4; ++n) {                      \
    bq[n][0] = *(const i32x4*)((bS) + n * 2048 + sk0);                 \
    bq[n][1] = *(const i32x4*)((bS) + n * 2048 + sk1);                 \
  }
#define RD_A(aS, q)                                                    \
  _Pragma("unroll") for (int m2 = 0; m2 < 2; ++m2) {                   \
    av[m2][0] = *(const i32x4*)((aS) + (2 * (q) + m2) * 2048 + sk0);   \
    av[m2][1] = *(const i32x4*)((aS) + (2 * (q) + m2) * 2048 + sk1);   \
  }
#define QMFMA(q)                                                       \
  do {                                                                 \
    __builtin_amdgcn_s_setprio(1);                                     \
    _Pragma("unroll") for (int m2 = 0; m2 < 2; ++m2)                   \
        _Pragma("unroll") for (int n = 0; n < 4; ++n) {                \
      acc[2 * (q) + m2][n] =                                           \
          MFMAI8(av[m2][0], bq[n][0], acc[2 * (q) + m2][n], 0, 0, 0);  \
      acc[2 * (q) + m2][n] =                                           \
          MFMAI8(av[m2][1], bq[n][1], acc[2 * (q) + m2][n], 0, 0, 0);  \
    }                                                                  \
    __builtin_amdgcn_s_setprio(0);                                     \
  } while (0)

  // Prologue: B(0), A(0), B(1) in FIFO order
  STAGE(bSrc0, 4, 0);
  STAGE(bSrc1, 5, 0);
  STAGE(aSrc0, 0, 0);
  STAGE(aSrc1, 1, 0);
  STAGE(bSrc0, 6, 128);
  STAGE(bSrc1, 7, 128);
  asm volatile("s_waitcnt vmcnt(4)" ::: "memory");  // step 0 resident
  BARRIER();

#pragma unroll 2
  for (int t = 0; t < NT; ++t) {
    const int par = t & 1;
    const char* aS = aSp0 + par * 32768;
    const char* bS = bSp0 + par * 32768;
    const int k1 = (t + 1) * 128, k2 = (t + 2) * 128;

    // stage A(t+1) into opposite-parity A slots (issue early)
    if (t + 1 < NT) {
      STAGE(aSrc0, (par ^ 1) * 2, k1);
      STAGE(aSrc1, (par ^ 1) * 2 + 1, k1);
    }

    // free-run region: compiler pipelines reads into MFMAs
    i32x4 bq[4][2], av[2][2];
    RD_B(bS);
    RD_A(aS, 0);
    QMFMA(0);
    RD_A(aS, 1);
    QMFMA(1);
    RD_A(aS, 2);
    QMFMA(2);
    RD_A(aS, 3);
    QMFMA(3);

    BARRIER();  // all waves' parity-par reads complete

    if (t + 2 < NT) {
      STAGE(bSrc0, 4 + par * 2, k2);
      STAGE(bSrc1, 4 + par * 2 + 1, k2);
      asm volatile("s_waitcnt vmcnt(4)" ::: "memory");  // step t+1 resident
    } else {
      asm volatile("s_waitcnt vmcnt(0)" ::: "memory");
    }
    if (t < NT - 1) BARRIER();  // gate block-wide
  }

  // ---- epilogue: C = scale_w * qrow[row] * acc ----
  const float sc = *scale_p;
  const int crow0 = tm * 256 + wr * 128 + fq * 4;
  const int ccol0 = tn * 256 + wc * 64 + fr;
#pragma unroll
  for (int m = 0; m < 8; ++m) {
    const int row = crow0 + m * 16;
    float q[4];
#pragma unroll
    for (int j = 0; j < 4; ++j) q[j] = sc * qrow[row + j];
#pragma unroll
    for (int n = 0; n < 4; ++n) {
      i32x4 v = acc[m][n];
      float* cp = C + (size_t)row * N + ccol0 + n * 16;
#pragma unroll
      for (int j = 0; j < 4; ++j) cp[(size_t)j * N] = (float)v[j] * q[j];
    }
  }
#undef STAGE
#undef RD_A
#undef RD_B
#undef QMFMA
}

extern "C" void kernel_launch(void* const* d_in, const int* in_sizes, int n_in,
                              void* d_out, int out_size, void* d_ws,
                              size_t ws_size, hipStream_t stream) {
  const float* x = (const float*)d_in[0];   // [8192][4096] f32
  const float* w = (const float*)d_in[1];   // [4096][4096] f32
  float* out = (float*)d_out;               // [8192][4096] f32

  char* ws = (char*)d_ws;
  char* xq = ws;                                   // 32 MiB
  char* sq = ws + 33554432;                        // 16 MiB
  float* qrow = (float*)(ws + 50331648);           // 8192 f32
  float* partials = (float*)(ws + 50331648 + 32768);  // 4096 f32
  float* scale = (float*)(ws + 50331648 + 32768 + 16384);

  wsign_kernel<<<4096, 256, 0, stream>>>(w, sq, partials);
  xquant_kernel<<<8192, 256, 0, stream>>>(x, xq, qrow);
  finalize_kernel<<<1, 256, 0, stream>>>(partials, scale);
  gemm_i8_kernel<<<512, 512, 0, stream>>>(xq, sq, scale, qrow, out);
}

// Round 11
// 176.280 us; speedup vs baseline: 1.0376x; 1.0376x over previous
//
#include <hip/hip_runtime.h>
#include <hip/hip_bf16.h>
#include <stdint.h>

typedef __attribute__((ext_vector_type(4))) int i32x4;

#define GLOAD(g, l) __builtin_amdgcn_global_load_lds(                      \
    (const __attribute__((address_space(1))) void*)(g),                    \
    (__attribute__((address_space(3))) void*)(l), 16, 0, 0)

#define MFMAI8 __builtin_amdgcn_mfma_i32_16x16x64_i8
#define BARRIER __builtin_amdgcn_s_barrier
#define LGKM0 asm volatile("s_waitcnt lgkmcnt(0)" ::: "memory")

// ---- W -> sign(W) as i8 {-1,0,1}, plus per-block partial sums of |W| ----
// Interleaved: lane reads float4 [base + tid + 256*i] -> dense 1KiB/wave
// per instruction; writes one int (4 x i8) at the same interleaved index.
__global__ __launch_bounds__(256) void wsign_kernel(
    const float* __restrict__ W, char* __restrict__ S,
    float* __restrict__ partials) {
  const int tid = threadIdx.x;
  const int base = blockIdx.x * 1024;  // block chunk: 1024 float4s
  const float4* wp = reinterpret_cast<const float4*>(W);
  int* sp = reinterpret_cast<int*>(S);
  float s = 0.f;
#pragma unroll
  for (int i = 0; i < 4; ++i) {
    const int idx = base + tid + 256 * i;
    float4 w = wp[idx];
    int b0 = (w.x > 0.f) - (w.x < 0.f);
    int b1 = (w.y > 0.f) - (w.y < 0.f);
    int b2 = (w.z > 0.f) - (w.z < 0.f);
    int b3 = (w.w > 0.f) - (w.w < 0.f);
    sp[idx] = (b0 & 255) | ((b1 & 255) << 8) | ((b2 & 255) << 16) |
              ((b3 & 255) << 24);
    s += fabsf(w.x) + fabsf(w.y) + fabsf(w.z) + fabsf(w.w);
  }
#pragma unroll
  for (int off = 32; off > 0; off >>= 1) s += __shfl_down(s, off, 64);
  __shared__ float sm[4];
  if ((tid & 63) == 0) sm[tid >> 6] = s;
  __syncthreads();
  if (tid == 0) partials[blockIdx.x] = sm[0] + sm[1] + sm[2] + sm[3];
}

// ---- x f32 -> i8 per-row quantization; qrow = amax/127 ------------------
// Interleaved: v[i] = row[tid + 256*i] (dense 1KiB/wave loads, 1KiB/wave
// int stores). Row-wide amax via shfl + LDS.
__global__ __launch_bounds__(256) void xquant_kernel(
    const float* __restrict__ X, char* __restrict__ XQ,
    float* __restrict__ qrow) {
  const int row = blockIdx.x;
  const int tid = threadIdx.x;
  const float4* xr = reinterpret_cast<const float4*>(X + (size_t)row * 4096);
  int* xo = reinterpret_cast<int*>(XQ + (size_t)row * 4096);
  float4 v[4];
  float am = 0.f;
#pragma unroll
  for (int i = 0; i < 4; ++i) {
    v[i] = xr[tid + 256 * i];
    am = fmaxf(am, fmaxf(fmaxf(fabsf(v[i].x), fabsf(v[i].y)),
                         fmaxf(fabsf(v[i].z), fabsf(v[i].w))));
  }
#pragma unroll
  for (int off = 1; off < 64; off <<= 1)
    am = fmaxf(am, __shfl_xor(am, off, 64));
  __shared__ float wm[4];
  if ((tid & 63) == 0) wm[tid >> 6] = am;
  __syncthreads();
  float amax = fmaxf(fmaxf(wm[0], wm[1]), fmaxf(wm[2], wm[3]));
  amax = fmaxf(amax, 1e-20f);
  const float rq = 127.f / amax;
#pragma unroll
  for (int i = 0; i < 4; ++i) {
    int b0 = __float2int_rn(v[i].x * rq);
    int b1 = __float2int_rn(v[i].y * rq);
    int b2 = __float2int_rn(v[i].z * rq);
    int b3 = __float2int_rn(v[i].w * rq);
    xo[tid + 256 * i] = (b0 & 255) | ((b1 & 255) << 8) | ((b2 & 255) << 16) |
                        ((b3 & 255) << 24);
  }
  if (tid == 0) qrow[row] = amax * (1.f / 127.f);
}

// ---- deterministic reduce of partials -> scale = mean(|W|) --------------
__global__ __launch_bounds__(256) void finalize_kernel(
    const float* __restrict__ partials, float* __restrict__ scale) {
  const int tid = threadIdx.x;
  float s = 0.f;
  for (int i = tid; i < 4096; i += 256) s += partials[i];
#pragma unroll
  for (int off = 32; off > 0; off >>= 1) s += __shfl_down(s, off, 64);
  __shared__ float sm[4];
  if ((tid & 63) == 0) sm[tid >> 6] = s;
  __syncthreads();
  if (tid == 0) scale[0] = (sm[0] + sm[1] + sm[2] + sm[3]) * (1.0f / 16777216.0f);
}

// ---- 256x256x128 8-wave 8-phase i8 GEMM, SINGLE barrier per phase -------
// (byte-identical to round 9 -- measured best: 125.7us, MfmaUtil 47.5%, 0
// bank conflicts. 8 one-barrier phases beat both 16-barrier (r7) and
// 4-barrier free-run (r10) variants.)
__global__ __launch_bounds__(512, 2) void gemm_i8_kernel(
    const char* __restrict__ A,  // [8192][4096] i8
    const char* __restrict__ B,  // [4096][4096] i8 sign
    const float* __restrict__ scale_p, const float* __restrict__ qrow,
    float* __restrict__ C) {
  constexpr int M = 8192, N = 4096, K = 4096;
  constexpr int NT = K / 128;  // 32 K-steps
  constexpr int NI = NT / 2;   // 16 iterations
  __shared__ __align__(16) char lds[131072];  // 8 slots x 16 KiB

  const int tid = threadIdx.x;
  const int wid = tid >> 6;
  const int lane = tid & 63;
  const int wr = wid >> 2;            // 0..1 : A half (M-rows)
  const int wc = wid & 3;             // 0..3 : 64-col group
  const int bh = wc >> 1;             // B half slot
  const int bsub = (wc & 1) * 8192;   // 64-row band within B half (bytes)
  const int fr = lane & 15;
  const int fq = lane >> 4;
  const int sk0 = ((fq) ^ (fr & 7)) * 16;
  const int sk1 = ((4 + fq) ^ (fr & 7)) * 16;

  const int bid = blockIdx.x;
  const int swz = (bid & 7) * 64 + (bid >> 3);
  const int tm = swz >> 4, tn = swz & 15;

  const int srow = tid >> 3;
  const int sg = (tid & 7) ^ (srow & 7);
  const char* aSrc0 = A + (size_t)(tm * 256 + srow) * K + sg * 16;
  const char* aSrc1 = aSrc0 + (size_t)128 * K;
  const char* bSrc0 = B + (size_t)(tn * 256 + srow) * K + sg * 16;
  const char* bSrc1 = bSrc0 + (size_t)128 * K;

#define STAGE(srcBase, slotIdx, koff)                              \
  do {                                                             \
    const char* _s = (srcBase) + (koff);                           \
    char* _d = lds + (slotIdx) * 16384 + wid * 1024;               \
    GLOAD(_s, _d);                                                 \
    GLOAD(_s + (size_t)64 * K, _d + 8192);                         \
  } while (0)

  const char* aSp0 = lds + (0 + wr) * 16384 + fr * 128;
  const char* aSp1 = lds + (2 + wr) * 16384 + fr * 128;
  const char* bSp0 = lds + (4 + bh) * 16384 + bsub + fr * 128;
  const char* bSp1 = lds + (6 + bh) * 16384 + bsub + fr * 128;

  i32x4 acc[8][4];
#pragma unroll
  for (int m = 0; m < 8; ++m)
#pragma unroll
    for (int n = 0; n < 4; ++n) acc[m][n] = (i32x4){0, 0, 0, 0};

#define RD_B(bS)                                                       \
  _Pragma("unroll") for (int n = 0; n < 4; ++n) {                      \
    bq[n][0] = *(const i32x4*)((bS) + n * 2048 + sk0);                 \
    bq[n][1] = *(const i32x4*)((bS) + n * 2048 + sk1);                 \
  }
#define RD_A(aS, q)                                                    \
  _Pragma("unroll") for (int m2 = 0; m2 < 2; ++m2) {                   \
    av[m2][0] = *(const i32x4*)((aS) + (2 * (q) + m2) * 2048 + sk0);   \
    av[m2][1] = *(const i32x4*)((aS) + (2 * (q) + m2) * 2048 + sk1);   \
  }
#define QMFMA(q)                                                       \
  do {                                                                 \
    __builtin_amdgcn_s_setprio(1);                                     \
    _Pragma("unroll") for (int m2 = 0; m2 < 2; ++m2)                   \
        _Pragma("unroll") for (int n = 0; n < 4; ++n) {                \
      acc[2 * (q) + m2][n] =                                           \
          MFMAI8(av[m2][0], bq[n][0], acc[2 * (q) + m2][n], 0, 0, 0);  \
      acc[2 * (q) + m2][n] =                                           \
          MFMAI8(av[m2][1], bq[n][1], acc[2 * (q) + m2][n], 0, 0, 0);  \
    }                                                                  \
    __builtin_amdgcn_s_setprio(0);                                     \
  } while (0)

  STAGE(bSrc0, 4, 0);     // B0(0)
  STAGE(bSrc1, 5, 0);     // B1(0)
  STAGE(aSrc0, 0, 0);     // A0(0)
  STAGE(aSrc1, 1, 0);     // A1(0)
  STAGE(bSrc0, 6, 128);   // B0(1)
  STAGE(bSrc1, 7, 128);   // B1(1)
  asm volatile("s_waitcnt vmcnt(4)" ::: "memory");  // step 0 resident
  BARRIER();

  for (int i = 0; i < NI; ++i) {
    const int t0 = 2 * i;
    const int k1 = (t0 + 1) * 128, k2 = (t0 + 2) * 128, k3 = (t0 + 3) * 128;
    i32x4 bq[4][2], av[2][2];

    // ---- P0: B(t0) + A q0; stage A0(t0+1) ----
    RD_B(bSp0);
    RD_A(aSp0, 0);
    STAGE(aSrc0, 2, k1);
    LGKM0; BARRIER(); QMFMA(0);

    // ---- P1: A q1; stage A1(t0+1) ----
    RD_A(aSp0, 1);
    STAGE(aSrc1, 3, k1);
    LGKM0; BARRIER(); QMFMA(1);

    // ---- P2: A q2; stage B0(t0+2) ----
    RD_A(aSp0, 2);
    if (t0 + 2 < NT) STAGE(bSrc0, 4, k2);
    LGKM0; BARRIER(); QMFMA(2);

    // ---- P3: A q3; stage B1(t0+2); GATE step t0+1 ----
    RD_A(aSp0, 3);
    if (t0 + 2 < NT) {
      STAGE(bSrc1, 5, k2);
      asm volatile("s_waitcnt vmcnt(4)" ::: "memory");
    } else {
      asm volatile("s_waitcnt vmcnt(0)" ::: "memory");
    }
    LGKM0; BARRIER(); QMFMA(3);

    // ---- P4: B(t0+1) + A q0; stage A0(t0+2) ----
    RD_B(bSp1);
    RD_A(aSp1, 0);
    if (t0 + 2 < NT) STAGE(aSrc0, 0, k2);
    LGKM0; BARRIER(); QMFMA(0);

    // ---- P5: A q1; stage A1(t0+2) ----
    RD_A(aSp1, 1);
    if (t0 + 2 < NT) STAGE(aSrc1, 1, k2);
    LGKM0; BARRIER(); QMFMA(1);

    // ---- P6: A q2; stage B0(t0+3) ----
    RD_A(aSp1, 2);
    if (t0 + 3 < NT) STAGE(bSrc0, 6, k3);
    LGKM0; BARRIER(); QMFMA(2);

    // ---- P7: A q3; stage B1(t0+3); GATE step t0+2 ----
    RD_A(aSp1, 3);
    if (t0 + 3 < NT) {
      STAGE(bSrc1, 7, k3);
      asm volatile("s_waitcnt vmcnt(4)" ::: "memory");
    }
    LGKM0; BARRIER(); QMFMA(3);
  }

  // ---- epilogue: C = scale_w * qrow[row] * acc ----
  const float sc = *scale_p;
  const int crow0 = tm * 256 + wr * 128 + fq * 4;
  const int ccol0 = tn * 256 + wc * 64 + fr;
#pragma unroll
  for (int m = 0; m < 8; ++m) {
    const int row = crow0 + m * 16;
    float q[4];
#pragma unroll
    for (int j = 0; j < 4; ++j) q[j] = sc * qrow[row + j];
#pragma unroll
    for (int n = 0; n < 4; ++n) {
      i32x4 v = acc[m][n];
      float* cp = C + (size_t)row * N + ccol0 + n * 16;
#pragma unroll
      for (int j = 0; j < 4; ++j) cp[(size_t)j * N] = (float)v[j] * q[j];
    }
  }
#undef STAGE
#undef RD_A
#undef RD_B
#undef QMFMA
}

extern "C" void kernel_launch(void* const* d_in, const int* in_sizes, int n_in,
                              void* d_out, int out_size, void* d_ws,
                              size_t ws_size, hipStream_t stream) {
  const float* x = (const float*)d_in[0];   // [8192][4096] f32
  const float* w = (const float*)d_in[1];   // [4096][4096] f32
  float* out = (float*)d_out;               // [8192][4096] f32

  char* ws = (char*)d_ws;
  char* xq = ws;                                   // 32 MiB
  char* sq = ws + 33554432;                        // 16 MiB
  float* qrow = (float*)(ws + 50331648);           // 8192 f32
  float* partials = (float*)(ws + 50331648 + 32768);  // 4096 f32
  float* scale = (float*)(ws + 50331648 + 32768 + 16384);

  wsign_kernel<<<4096, 256, 0, stream>>>(w, sq, partials);
  xquant_kernel<<<8192, 256, 0, stream>>>(x, xq, qrow);
  finalize_kernel<<<1, 256, 0, stream>>>(partials, scale);
  gemm_i8_kernel<<<512, 512, 0, stream>>>(xq, sq, scale, qrow, out);
}

// Round 12
// 174.788 us; speedup vs baseline: 1.0465x; 1.0085x over previous
//
#include <hip/hip_runtime.h>
#include <hip/hip_bf16.h>
#include <stdint.h>

typedef __attribute__((ext_vector_type(4))) int i32x4;

#define GLOAD(g, l) __builtin_amdgcn_global_load_lds(                      \
    (const __attribute__((address_space(1))) void*)(g),                    \
    (__attribute__((address_space(3))) void*)(l), 16, 0, 0)

#define MFMAI8 __builtin_amdgcn_mfma_i32_16x16x64_i8
#define BARRIER __builtin_amdgcn_s_barrier

// ---- W -> sign(W) as i8 {-1,0,1}, plus per-block partial sums of |W| ----
__global__ __launch_bounds__(256) void wsign_kernel(
    const float* __restrict__ W, char* __restrict__ S,
    float* __restrict__ partials) {
  const int tid = threadIdx.x;
  const int base = blockIdx.x * 1024;
  const float4* wp = reinterpret_cast<const float4*>(W);
  int* sp = reinterpret_cast<int*>(S);
  float s = 0.f;
#pragma unroll
  for (int i = 0; i < 4; ++i) {
    const int idx = base + tid + 256 * i;
    float4 w = wp[idx];
    int b0 = (w.x > 0.f) - (w.x < 0.f);
    int b1 = (w.y > 0.f) - (w.y < 0.f);
    int b2 = (w.z > 0.f) - (w.z < 0.f);
    int b3 = (w.w > 0.f) - (w.w < 0.f);
    sp[idx] = (b0 & 255) | ((b1 & 255) << 8) | ((b2 & 255) << 16) |
              ((b3 & 255) << 24);
    s += fabsf(w.x) + fabsf(w.y) + fabsf(w.z) + fabsf(w.w);
  }
#pragma unroll
  for (int off = 32; off > 0; off >>= 1) s += __shfl_down(s, off, 64);
  __shared__ float sm[4];
  if ((tid & 63) == 0) sm[tid >> 6] = s;
  __syncthreads();
  if (tid == 0) partials[blockIdx.x] = sm[0] + sm[1] + sm[2] + sm[3];
}

// ---- x f32 -> i8 per-row quantization; qrow = amax/127 ------------------
__global__ __launch_bounds__(256) void xquant_kernel(
    const float* __restrict__ X, char* __restrict__ XQ,
    float* __restrict__ qrow) {
  const int row = blockIdx.x;
  const int tid = threadIdx.x;
  const float4* xr = reinterpret_cast<const float4*>(X + (size_t)row * 4096);
  int* xo = reinterpret_cast<int*>(XQ + (size_t)row * 4096);
  float4 v[4];
  float am = 0.f;
#pragma unroll
  for (int i = 0; i < 4; ++i) {
    v[i] = xr[tid + 256 * i];
    am = fmaxf(am, fmaxf(fmaxf(fabsf(v[i].x), fabsf(v[i].y)),
                         fmaxf(fabsf(v[i].z), fabsf(v[i].w))));
  }
#pragma unroll
  for (int off = 1; off < 64; off <<= 1)
    am = fmaxf(am, __shfl_xor(am, off, 64));
  __shared__ float wm[4];
  if ((tid & 63) == 0) wm[tid >> 6] = am;
  __syncthreads();
  float amax = fmaxf(fmaxf(wm[0], wm[1]), fmaxf(wm[2], wm[3]));
  amax = fmaxf(amax, 1e-20f);
  const float rq = 127.f / amax;
#pragma unroll
  for (int i = 0; i < 4; ++i) {
    int b0 = __float2int_rn(v[i].x * rq);
    int b1 = __float2int_rn(v[i].y * rq);
    int b2 = __float2int_rn(v[i].z * rq);
    int b3 = __float2int_rn(v[i].w * rq);
    xo[tid + 256 * i] = (b0 & 255) | ((b1 & 255) << 8) | ((b2 & 255) << 16) |
                        ((b3 & 255) << 24);
  }
  if (tid == 0) qrow[row] = amax * (1.f / 127.f);
}

// ---- deterministic reduce of partials -> scale = mean(|W|) --------------
__global__ __launch_bounds__(256) void finalize_kernel(
    const float* __restrict__ partials, float* __restrict__ scale) {
  const int tid = threadIdx.x;
  float s = 0.f;
  for (int i = tid; i < 4096; i += 256) s += partials[i];
#pragma unroll
  for (int off = 32; off > 0; off >>= 1) s += __shfl_down(s, off, 64);
  __shared__ float sm[4];
  if ((tid & 63) == 0) sm[tid >> 6] = s;
  __syncthreads();
  if (tid == 0) scale[0] = (sm[0] + sm[1] + sm[2] + sm[3]) * (1.0f / 16777216.0f);
}

// ---- 256x256x128 8-wave 8-phase i8 GEMM, read-hoisted pipeline ----------
// Each phase: {issue next-quadrant ds_reads; 1 half-tile stage; [vmcnt];
//              BARRIER; MFMA current quadrant (compiler-counted lgkm)}.
// Reads lead MFMA by one phase -> LDS pipe overlaps matrix pipe.
// Stage map (iter i, t0=2i): Ph0:B1(t0+1)s7 Ph1:A0(t0+1)s2 Ph2:A1(t0+1)s3
//  Ph3:B0(t0+2)s4 Ph4:B1(t0+2)s5 Ph5:A0(t0+2)s0 Ph6:A1(t0+2)s1
//  Ph7:B0(t0+3)s6.  Hazards: every stage target's last-reader MFMA is >=1
//  barrier before the stage (audited per-slot). Gates vmcnt(2)@Ph3/Ph7
//  (FIFO: 10/8 outstanding, drain 8/6 oldest = next step's half-tiles);
//  cross-step ds_reads only AFTER the gate's barrier (block-wide).
__global__ __launch_bounds__(512, 2) void gemm_i8_kernel(
    const char* __restrict__ A,  // [8192][4096] i8
    const char* __restrict__ B,  // [4096][4096] i8 sign
    const float* __restrict__ scale_p, const float* __restrict__ qrow,
    float* __restrict__ C) {
  constexpr int M = 8192, N = 4096, K = 4096;
  constexpr int NT = K / 128;  // 32 K-steps
  constexpr int NI = NT / 2;   // 16 iterations
  __shared__ __align__(16) char lds[131072];  // 8 slots x 16 KiB

  const int tid = threadIdx.x;
  const int wid = tid >> 6;
  const int lane = tid & 63;
  const int wr = wid >> 2;            // 0..1 : A half (M-rows)
  const int wc = wid & 3;             // 0..3 : 64-col group
  const int bh = wc >> 1;             // B half slot
  const int bsub = (wc & 1) * 8192;   // 64-row band within B half (bytes)
  const int fr = lane & 15;
  const int fq = lane >> 4;
  const int sk0 = ((fq) ^ (fr & 7)) * 16;
  const int sk1 = ((4 + fq) ^ (fr & 7)) * 16;

  const int bid = blockIdx.x;
  const int swz = (bid & 7) * 64 + (bid >> 3);
  const int tm = swz >> 4, tn = swz & 15;

  const int srow = tid >> 3;
  const int sg = (tid & 7) ^ (srow & 7);
  const char* aSrc0 = A + (size_t)(tm * 256 + srow) * K + sg * 16;
  const char* aSrc1 = aSrc0 + (size_t)128 * K;
  const char* bSrc0 = B + (size_t)(tn * 256 + srow) * K + sg * 16;
  const char* bSrc1 = bSrc0 + (size_t)128 * K;

#define STAGE(srcBase, slotIdx, koff)                              \
  do {                                                             \
    const char* _s = (srcBase) + (koff);                           \
    char* _d = lds + (slotIdx) * 16384 + wid * 1024;               \
    GLOAD(_s, _d);                                                 \
    GLOAD(_s + (size_t)64 * K, _d + 8192);                         \
  } while (0)

  const char* aSp0 = lds + (0 + wr) * 16384 + fr * 128;
  const char* aSp1 = lds + (2 + wr) * 16384 + fr * 128;
  const char* bSp0 = lds + (4 + bh) * 16384 + bsub + fr * 128;
  const char* bSp1 = lds + (6 + bh) * 16384 + bsub + fr * 128;

  i32x4 acc[8][4];
#pragma unroll
  for (int m = 0; m < 8; ++m)
#pragma unroll
    for (int n = 0; n < 4; ++n) acc[m][n] = (i32x4){0, 0, 0, 0};

#define RD_B(bS)                                                       \
  _Pragma("unroll") for (int n = 0; n < 4; ++n) {                      \
    bq[n][0] = *(const i32x4*)((bS) + n * 2048 + sk0);                 \
    bq[n][1] = *(const i32x4*)((bS) + n * 2048 + sk1);                 \
  }
#define RD_A(dst, aS, q)                                               \
  _Pragma("unroll") for (int m2 = 0; m2 < 2; ++m2) {                   \
    dst[m2][0] = *(const i32x4*)((aS) + (2 * (q) + m2) * 2048 + sk0);  \
    dst[m2][1] = *(const i32x4*)((aS) + (2 * (q) + m2) * 2048 + sk1);  \
  }
#define QMFMA(av, q)                                                   \
  do {                                                                 \
    __builtin_amdgcn_s_setprio(1);                                     \
    _Pragma("unroll") for (int m2 = 0; m2 < 2; ++m2)                   \
        _Pragma("unroll") for (int n = 0; n < 4; ++n) {                \
      acc[2 * (q) + m2][n] =                                           \
          MFMAI8(av[m2][0], bq[n][0], acc[2 * (q) + m2][n], 0, 0, 0);  \
      acc[2 * (q) + m2][n] =                                           \
          MFMAI8(av[m2][1], bq[n][1], acc[2 * (q) + m2][n], 0, 0, 0);  \
    }                                                                  \
    __builtin_amdgcn_s_setprio(0);                                     \
  } while (0)

  // Prologue: step0 (4 halves) + B0(1); gate leaves B0(1) in flight;
  // then issue step0's B + A(q0) reads (post-barrier = block-wide resident).
  STAGE(bSrc0, 4, 0);
  STAGE(bSrc1, 5, 0);
  STAGE(aSrc0, 0, 0);
  STAGE(aSrc1, 1, 0);
  STAGE(bSrc0, 6, 128);
  asm volatile("s_waitcnt vmcnt(2)" ::: "memory");
  BARRIER();

  i32x4 bq[4][2], av0[2][2], av1[2][2];
  RD_B(bSp0);
  RD_A(av0, aSp0, 0);

  for (int i = 0; i < NI; ++i) {
    const int t0 = 2 * i;
    const int k1 = (t0 + 1) * 128, k2 = (t0 + 2) * 128, k3 = (t0 + 3) * 128;

    // ---- Ph0: issue A q1; stage B1(t0+1)->s7; MFMA q0 ----
    RD_A(av1, aSp0, 1);
    STAGE(bSrc1, 7, k1);
    BARRIER();
    QMFMA(av0, 0);

    // ---- Ph1: issue A q2; stage A0(t0+1)->s2; MFMA q1 ----
    RD_A(av0, aSp0, 2);
    STAGE(aSrc0, 2, k1);
    BARRIER();
    QMFMA(av1, 1);

    // ---- Ph2: issue A q3; stage A1(t0+1)->s3; MFMA q2 ----
    RD_A(av1, aSp0, 3);
    STAGE(aSrc1, 3, k1);
    BARRIER();
    QMFMA(av0, 2);

    // ---- Ph3: stage B0(t0+2)->s4; GATE step t0+1; MFMA q3;
    //      then issue step t0+1's B + A q0 (post-barrier) ----
    if (t0 + 2 < NT) {
      STAGE(bSrc0, 4, k2);
      asm volatile("s_waitcnt vmcnt(2)" ::: "memory");
    } else {
      asm volatile("s_waitcnt vmcnt(0)" ::: "memory");
    }
    BARRIER();
    QMFMA(av1, 3);
    RD_B(bSp1);
    RD_A(av0, aSp1, 0);

    // ---- Ph4: issue A q1; stage B1(t0+2)->s5; MFMA q0 ----
    RD_A(av1, aSp1, 1);
    if (t0 + 2 < NT) STAGE(bSrc1, 5, k2);
    BARRIER();
    QMFMA(av0, 0);

    // ---- Ph5: issue A q2; stage A0(t0+2)->s0; MFMA q1 ----
    RD_A(av0, aSp1, 2);
    if (t0 + 2 < NT) STAGE(aSrc0, 0, k2);
    BARRIER();
    QMFMA(av1, 1);

    // ---- Ph6: issue A q3; stage A1(t0+2)->s1; MFMA q2 ----
    RD_A(av1, aSp1, 3);
    if (t0 + 2 < NT) STAGE(aSrc1, 1, k2);
    BARRIER();
    QMFMA(av0, 2);

    // ---- Ph7: stage B0(t0+3)->s6; GATE step t0+2; MFMA q3;
    //      then issue step t0+2's B + A q0 ----
    if (t0 + 2 < NT) {
      STAGE(bSrc0, 6, k3);
      asm volatile("s_waitcnt vmcnt(2)" ::: "memory");
    }
    BARRIER();
    QMFMA(av1, 3);
    if (t0 + 2 < NT) {
      RD_B(bSp0);
      RD_A(av0, aSp0, 0);
    }
  }

  // ---- epilogue: C = scale_w * qrow[row] * acc ----
  const float sc = *scale_p;
  const int crow0 = tm * 256 + wr * 128 + fq * 4;
  const int ccol0 = tn * 256 + wc * 64 + fr;
#pragma unroll
  for (int m = 0; m < 8; ++m) {
    const int row = crow0 + m * 16;
    float q[4];
#pragma unroll
    for (int j = 0; j < 4; ++j) q[j] = sc * qrow[row + j];
#pragma unroll
    for (int n = 0; n < 4; ++n) {
      i32x4 v = acc[m][n];
      float* cp = C + (size_t)row * N + ccol0 + n * 16;
#pragma unroll
      for (int j = 0; j < 4; ++j) cp[(size_t)j * N] = (float)v[j] * q[j];
    }
  }
#undef STAGE
#undef RD_A
#undef RD_B
#undef QMFMA
}

extern "C" void kernel_launch(void* const* d_in, const int* in_sizes, int n_in,
                              void* d_out, int out_size, void* d_ws,
                              size_t ws_size, hipStream_t stream) {
  const float* x = (const float*)d_in[0];   // [8192][4096] f32
  const float* w = (const float*)d_in[1];   // [4096][4096] f32
  float* out = (float*)d_out;               // [8192][4096] f32

  char* ws = (char*)d_ws;
  char* xq = ws;                                   // 32 MiB
  char* sq = ws + 33554432;                        // 16 MiB
  float* qrow = (float*)(ws + 50331648);           // 8192 f32
  float* partials = (float*)(ws + 50331648 + 32768);  // 4096 f32
  float* scale = (float*)(ws + 50331648 + 32768 + 16384);

  wsign_kernel<<<4096, 256, 0, stream>>>(w, sq, partials);
  xquant_kernel<<<8192, 256, 0, stream>>>(x, xq, qrow);
  finalize_kernel<<<1, 256, 0, stream>>>(partials, scale);
  gemm_i8_kernel<<<512, 512, 0, stream>>>(xq, sq, scale, qrow, out);
}

// Round 13
// 172.110 us; speedup vs baseline: 1.0627x; 1.0156x over previous
//
#include <hip/hip_runtime.h>
#include <hip/hip_bf16.h>
#include <stdint.h>

typedef __attribute__((ext_vector_type(4))) int i32x4;

#define GLOAD(g, l) __builtin_amdgcn_global_load_lds(                      \
    (const __attribute__((address_space(1))) void*)(g),                    \
    (__attribute__((address_space(3))) void*)(l), 16, 0, 0)

#define MFMAI8 __builtin_amdgcn_mfma_i32_16x16x64_i8
#define BARRIER __builtin_amdgcn_s_barrier

// ---- fused prep: blocks 0..8191 = xquant rows; 8192..12287 = wsign ------
__global__ __launch_bounds__(256) void prep_kernel(
    const float* __restrict__ X, const float* __restrict__ W,
    char* __restrict__ XQ, char* __restrict__ SQ,
    float* __restrict__ qrow, float* __restrict__ partials) {
  const int b = blockIdx.x;
  const int tid = threadIdx.x;
  if (b < 8192) {
    // ---- xquant: one row, per-row amax -> i8 ----
    const int row = b;
    const float4* xr =
        reinterpret_cast<const float4*>(X + (size_t)row * 4096);
    int* xo = reinterpret_cast<int*>(XQ + (size_t)row * 4096);
    float4 v[4];
    float am = 0.f;
#pragma unroll
    for (int i = 0; i < 4; ++i) {
      v[i] = xr[tid + 256 * i];
      am = fmaxf(am, fmaxf(fmaxf(fabsf(v[i].x), fabsf(v[i].y)),
                           fmaxf(fabsf(v[i].z), fabsf(v[i].w))));
    }
#pragma unroll
    for (int off = 1; off < 64; off <<= 1)
      am = fmaxf(am, __shfl_xor(am, off, 64));
    __shared__ float wm[4];
    if ((tid & 63) == 0) wm[tid >> 6] = am;
    __syncthreads();
    float amax = fmaxf(fmaxf(wm[0], wm[1]), fmaxf(wm[2], wm[3]));
    amax = fmaxf(amax, 1e-20f);
    const float rq = 127.f / amax;
#pragma unroll
    for (int i = 0; i < 4; ++i) {
      int b0 = __float2int_rn(v[i].x * rq);
      int b1 = __float2int_rn(v[i].y * rq);
      int b2 = __float2int_rn(v[i].z * rq);
      int b3 = __float2int_rn(v[i].w * rq);
      xo[tid + 256 * i] = (b0 & 255) | ((b1 & 255) << 8) |
                          ((b2 & 255) << 16) | ((b3 & 255) << 24);
    }
    if (tid == 0) qrow[row] = amax * (1.f / 127.f);
  } else {
    // ---- wsign: sign(W) -> i8, partial |W| sums ----
    const int base = (b - 8192) * 1024;
    const float4* wp = reinterpret_cast<const float4*>(W);
    int* sp = reinterpret_cast<int*>(SQ);
    float s = 0.f;
#pragma unroll
    for (int i = 0; i < 4; ++i) {
      const int idx = base + tid + 256 * i;
      float4 w = wp[idx];
      int b0 = (w.x > 0.f) - (w.x < 0.f);
      int b1 = (w.y > 0.f) - (w.y < 0.f);
      int b2 = (w.z > 0.f) - (w.z < 0.f);
      int b3 = (w.w > 0.f) - (w.w < 0.f);
      sp[idx] = (b0 & 255) | ((b1 & 255) << 8) | ((b2 & 255) << 16) |
                ((b3 & 255) << 24);
      s += fabsf(w.x) + fabsf(w.y) + fabsf(w.z) + fabsf(w.w);
    }
#pragma unroll
    for (int off = 32; off > 0; off >>= 1) s += __shfl_down(s, off, 64);
    __shared__ float sm[4];
    if ((tid & 63) == 0) sm[tid >> 6] = s;
    __syncthreads();
    if (tid == 0) partials[b - 8192] = sm[0] + sm[1] + sm[2] + sm[3];
  }
}

// ---- deterministic reduce of partials -> scale = mean(|W|) --------------
__global__ __launch_bounds__(256) void finalize_kernel(
    const float* __restrict__ partials, float* __restrict__ scale) {
  const int tid = threadIdx.x;
  float s = 0.f;
  for (int i = tid; i < 4096; i += 256) s += partials[i];
#pragma unroll
  for (int off = 32; off > 0; off >>= 1) s += __shfl_down(s, off, 64);
  __shared__ float sm[4];
  if ((tid & 63) == 0) sm[tid >> 6] = s;
  __syncthreads();
  if (tid == 0) scale[0] = (sm[0] + sm[1] + sm[2] + sm[3]) * (1.0f / 16777216.0f);
}

// ---- 256x256x128 8-wave 8-phase i8 GEMM, read-hoisted pipeline ----------
// (byte-identical to round 12 -- measured best: 119.3us, MfmaUtil 49.3%,
//  0 bank conflicts, at the serialized MFMA+LDS floor for this structure.)
__global__ __launch_bounds__(512, 2) void gemm_i8_kernel(
    const char* __restrict__ A,  // [8192][4096] i8
    const char* __restrict__ B,  // [4096][4096] i8 sign
    const float* __restrict__ scale_p, const float* __restrict__ qrow,
    float* __restrict__ C) {
  constexpr int M = 8192, N = 4096, K = 4096;
  constexpr int NT = K / 128;  // 32 K-steps
  constexpr int NI = NT / 2;   // 16 iterations
  __shared__ __align__(16) char lds[131072];  // 8 slots x 16 KiB

  const int tid = threadIdx.x;
  const int wid = tid >> 6;
  const int lane = tid & 63;
  const int wr = wid >> 2;            // 0..1 : A half (M-rows)
  const int wc = wid & 3;             // 0..3 : 64-col group
  const int bh = wc >> 1;             // B half slot
  const int bsub = (wc & 1) * 8192;   // 64-row band within B half (bytes)
  const int fr = lane & 15;
  const int fq = lane >> 4;
  const int sk0 = ((fq) ^ (fr & 7)) * 16;
  const int sk1 = ((4 + fq) ^ (fr & 7)) * 16;

  const int bid = blockIdx.x;
  const int swz = (bid & 7) * 64 + (bid >> 3);
  const int tm = swz >> 4, tn = swz & 15;

  const int srow = tid >> 3;
  const int sg = (tid & 7) ^ (srow & 7);
  const char* aSrc0 = A + (size_t)(tm * 256 + srow) * K + sg * 16;
  const char* aSrc1 = aSrc0 + (size_t)128 * K;
  const char* bSrc0 = B + (size_t)(tn * 256 + srow) * K + sg * 16;
  const char* bSrc1 = bSrc0 + (size_t)128 * K;

#define STAGE(srcBase, slotIdx, koff)                              \
  do {                                                             \
    const char* _s = (srcBase) + (koff);                           \
    char* _d = lds + (slotIdx) * 16384 + wid * 1024;               \
    GLOAD(_s, _d);                                                 \
    GLOAD(_s + (size_t)64 * K, _d + 8192);                         \
  } while (0)

  const char* aSp0 = lds + (0 + wr) * 16384 + fr * 128;
  const char* aSp1 = lds + (2 + wr) * 16384 + fr * 128;
  const char* bSp0 = lds + (4 + bh) * 16384 + bsub + fr * 128;
  const char* bSp1 = lds + (6 + bh) * 16384 + bsub + fr * 128;

  i32x4 acc[8][4];
#pragma unroll
  for (int m = 0; m < 8; ++m)
#pragma unroll
    for (int n = 0; n < 4; ++n) acc[m][n] = (i32x4){0, 0, 0, 0};

#define RD_B(bS)                                                       \
  _Pragma("unroll") for (int n = 0; n < 4; ++n) {                      \
    bq[n][0] = *(const i32x4*)((bS) + n * 2048 + sk0);                 \
    bq[n][1] = *(const i32x4*)((bS) + n * 2048 + sk1);                 \
  }
#define RD_A(dst, aS, q)                                               \
  _Pragma("unroll") for (int m2 = 0; m2 < 2; ++m2) {                   \
    dst[m2][0] = *(const i32x4*)((aS) + (2 * (q) + m2) * 2048 + sk0);  \
    dst[m2][1] = *(const i32x4*)((aS) + (2 * (q) + m2) * 2048 + sk1);  \
  }
#define QMFMA(av, q)                                                   \
  do {                                                                 \
    __builtin_amdgcn_s_setprio(1);                                     \
    _Pragma("unroll") for (int m2 = 0; m2 < 2; ++m2)                   \
        _Pragma("unroll") for (int n = 0; n < 4; ++n) {                \
      acc[2 * (q) + m2][n] =                                           \
          MFMAI8(av[m2][0], bq[n][0], acc[2 * (q) + m2][n], 0, 0, 0);  \
      acc[2 * (q) + m2][n] =                                           \
          MFMAI8(av[m2][1], bq[n][1], acc[2 * (q) + m2][n], 0, 0, 0);  \
    }                                                                  \
    __builtin_amdgcn_s_setprio(0);                                     \
  } while (0)

  STAGE(bSrc0, 4, 0);
  STAGE(bSrc1, 5, 0);
  STAGE(aSrc0, 0, 0);
  STAGE(aSrc1, 1, 0);
  STAGE(bSrc0, 6, 128);
  asm volatile("s_waitcnt vmcnt(2)" ::: "memory");
  BARRIER();

  i32x4 bq[4][2], av0[2][2], av1[2][2];
  RD_B(bSp0);
  RD_A(av0, aSp0, 0);

  for (int i = 0; i < NI; ++i) {
    const int t0 = 2 * i;
    const int k1 = (t0 + 1) * 128, k2 = (t0 + 2) * 128, k3 = (t0 + 3) * 128;

    // ---- Ph0: issue A q1; stage B1(t0+1)->s7; MFMA q0 ----
    RD_A(av1, aSp0, 1);
    STAGE(bSrc1, 7, k1);
    BARRIER();
    QMFMA(av0, 0);

    // ---- Ph1: issue A q2; stage A0(t0+1)->s2; MFMA q1 ----
    RD_A(av0, aSp0, 2);
    STAGE(aSrc0, 2, k1);
    BARRIER();
    QMFMA(av1, 1);

    // ---- Ph2: issue A q3; stage A1(t0+1)->s3; MFMA q2 ----
    RD_A(av1, aSp0, 3);
    STAGE(aSrc1, 3, k1);
    BARRIER();
    QMFMA(av0, 2);

    // ---- Ph3: stage B0(t0+2)->s4; GATE step t0+1; MFMA q3;
    //      then issue step t0+1's B + A q0 (post-barrier) ----
    if (t0 + 2 < NT) {
      STAGE(bSrc0, 4, k2);
      asm volatile("s_waitcnt vmcnt(2)" ::: "memory");
    } else {
      asm volatile("s_waitcnt vmcnt(0)" ::: "memory");
    }
    BARRIER();
    QMFMA(av1, 3);
    RD_B(bSp1);
    RD_A(av0, aSp1, 0);

    // ---- Ph4: issue A q1; stage B1(t0+2)->s5; MFMA q0 ----
    RD_A(av1, aSp1, 1);
    if (t0 + 2 < NT) STAGE(bSrc1, 5, k2);
    BARRIER();
    QMFMA(av0, 0);

    // ---- Ph5: issue A q2; stage A0(t0+2)->s0; MFMA q1 ----
    RD_A(av0, aSp1, 2);
    if (t0 + 2 < NT) STAGE(aSrc0, 0, k2);
    BARRIER();
    QMFMA(av1, 1);

    // ---- Ph6: issue A q3; stage A1(t0+2)->s1; MFMA q2 ----
    RD_A(av1, aSp1, 3);
    if (t0 + 2 < NT) STAGE(aSrc1, 1, k2);
    BARRIER();
    QMFMA(av0, 2);

    // ---- Ph7: stage B0(t0+3)->s6; GATE step t0+2; MFMA q3;
    //      then issue step t0+2's B + A q0 ----
    if (t0 + 2 < NT) {
      STAGE(bSrc0, 6, k3);
      asm volatile("s_waitcnt vmcnt(2)" ::: "memory");
    }
    BARRIER();
    QMFMA(av1, 3);
    if (t0 + 2 < NT) {
      RD_B(bSp0);
      RD_A(av0, aSp0, 0);
    }
  }

  // ---- epilogue: C = scale_w * qrow[row] * acc ----
  const float sc = *scale_p;
  const int crow0 = tm * 256 + wr * 128 + fq * 4;
  const int ccol0 = tn * 256 + wc * 64 + fr;
#pragma unroll
  for (int m = 0; m < 8; ++m) {
    const int row = crow0 + m * 16;
    float q[4];
#pragma unroll
    for (int j = 0; j < 4; ++j) q[j] = sc * qrow[row + j];
#pragma unroll
    for (int n = 0; n < 4; ++n) {
      i32x4 v = acc[m][n];
      float* cp = C + (size_t)row * N + ccol0 + n * 16;
#pragma unroll
      for (int j = 0; j < 4; ++j) cp[(size_t)j * N] = (float)v[j] * q[j];
    }
  }
#undef STAGE
#undef RD_A
#undef RD_B
#undef QMFMA
}

extern "C" void kernel_launch(void* const* d_in, const int* in_sizes, int n_in,
                              void* d_out, int out_size, void* d_ws,
                              size_t ws_size, hipStream_t stream) {
  const float* x = (const float*)d_in[0];   // [8192][4096] f32
  const float* w = (const float*)d_in[1];   // [4096][4096] f32
  float* out = (float*)d_out;               // [8192][4096] f32

  char* ws = (char*)d_ws;
  char* xq = ws;                                   // 32 MiB
  char* sq = ws + 33554432;                        // 16 MiB
  float* qrow = (float*)(ws + 50331648);           // 8192 f32
  float* partials = (float*)(ws + 50331648 + 32768);  // 4096 f32
  float* scale = (float*)(ws + 50331648 + 32768 + 16384);

  prep_kernel<<<12288, 256, 0, stream>>>(x, w, xq, sq, qrow, partials);
  finalize_kernel<<<1, 256, 0, stream>>>(partials, scale);
  gemm_i8_kernel<<<512, 512, 0, stream>>>(xq, sq, scale, qrow, out);
}

// Round 14
// 170.920 us; speedup vs baseline: 1.0701x; 1.0070x over previous
//
#include <hip/hip_runtime.h>
#include <hip/hip_bf16.h>
#include <stdint.h>

typedef __attribute__((ext_vector_type(4))) int i32x4;

#define GLOAD(g, l) __builtin_amdgcn_global_load_lds(                      \
    (const __attribute__((address_space(1))) void*)(g),                    \
    (__attribute__((address_space(3))) void*)(l), 16, 0, 0)

#define MFMAI8 __builtin_amdgcn_mfma_i32_16x16x64_i8
#define BARRIER __builtin_amdgcn_s_barrier

// ---- 256x256x128 8-wave 8-phase i8 GEMM, read-hoisted pipeline ----------
// (K-loop byte-identical to round 12's 119.3us/49.3% MfmaUtil version.
//  Compiled FIRST in the TU to shield its codegen from sibling kernels
//  (rule #19 perturbation suspected in r13's 129us sag). Epilogue now
//  reduces partials[4096] per-block (fixed order -> bit-identical scale)
//  so the finalize dispatch is gone.)
__global__ __launch_bounds__(512, 2) void gemm_i8_kernel(
    const char* __restrict__ A,  // [8192][4096] i8
    const char* __restrict__ B,  // [4096][4096] i8 sign
    const float* __restrict__ partials, const float* __restrict__ qrow,
    float* __restrict__ C) {
  constexpr int M = 8192, N = 4096, K = 4096;
  constexpr int NT = K / 128;  // 32 K-steps
  constexpr int NI = NT / 2;   // 16 iterations
  __shared__ __align__(16) char lds[131072];  // 8 slots x 16 KiB

  const int tid = threadIdx.x;
  const int wid = tid >> 6;
  const int lane = tid & 63;
  const int wr = wid >> 2;            // 0..1 : A half (M-rows)
  const int wc = wid & 3;             // 0..3 : 64-col group
  const int bh = wc >> 1;             // B half slot
  const int bsub = (wc & 1) * 8192;   // 64-row band within B half (bytes)
  const int fr = lane & 15;
  const int fq = lane >> 4;
  const int sk0 = ((fq) ^ (fr & 7)) * 16;
  const int sk1 = ((4 + fq) ^ (fr & 7)) * 16;

  const int bid = blockIdx.x;
  const int swz = (bid & 7) * 64 + (bid >> 3);
  const int tm = swz >> 4, tn = swz & 15;

  const int srow = tid >> 3;
  const int sg = (tid & 7) ^ (srow & 7);
  const char* aSrc0 = A + (size_t)(tm * 256 + srow) * K + sg * 16;
  const char* aSrc1 = aSrc0 + (size_t)128 * K;
  const char* bSrc0 = B + (size_t)(tn * 256 + srow) * K + sg * 16;
  const char* bSrc1 = bSrc0 + (size_t)128 * K;

#define STAGE(srcBase, slotIdx, koff)                              \
  do {                                                             \
    const char* _s = (srcBase) + (koff);                           \
    char* _d = lds + (slotIdx) * 16384 + wid * 1024;               \
    GLOAD(_s, _d);                                                 \
    GLOAD(_s + (size_t)64 * K, _d + 8192);                         \
  } while (0)

  const char* aSp0 = lds + (0 + wr) * 16384 + fr * 128;
  const char* aSp1 = lds + (2 + wr) * 16384 + fr * 128;
  const char* bSp0 = lds + (4 + bh) * 16384 + bsub + fr * 128;
  const char* bSp1 = lds + (6 + bh) * 16384 + bsub + fr * 128;

  i32x4 acc[8][4];
#pragma unroll
  for (int m = 0; m < 8; ++m)
#pragma unroll
    for (int n = 0; n < 4; ++n) acc[m][n] = (i32x4){0, 0, 0, 0};

#define RD_B(bS)                                                       \
  _Pragma("unroll") for (int n = 0; n < 4; ++n) {                      \
    bq[n][0] = *(const i32x4*)((bS) + n * 2048 + sk0);                 \
    bq[n][1] = *(const i32x4*)((bS) + n * 2048 + sk1);                 \
  }
#define RD_A(dst, aS, q)                                               \
  _Pragma("unroll") for (int m2 = 0; m2 < 2; ++m2) {                   \
    dst[m2][0] = *(const i32x4*)((aS) + (2 * (q) + m2) * 2048 + sk0);  \
    dst[m2][1] = *(const i32x4*)((aS) + (2 * (q) + m2) * 2048 + sk1);  \
  }
#define QMFMA(av, q)                                                   \
  do {                                                                 \
    __builtin_amdgcn_s_setprio(1);                                     \
    _Pragma("unroll") for (int m2 = 0; m2 < 2; ++m2)                   \
        _Pragma("unroll") for (int n = 0; n < 4; ++n) {                \
      acc[2 * (q) + m2][n] =                                           \
          MFMAI8(av[m2][0], bq[n][0], acc[2 * (q) + m2][n], 0, 0, 0);  \
      acc[2 * (q) + m2][n] =                                           \
          MFMAI8(av[m2][1], bq[n][1], acc[2 * (q) + m2][n], 0, 0, 0);  \
    }                                                                  \
    __builtin_amdgcn_s_setprio(0);                                     \
  } while (0)

  STAGE(bSrc0, 4, 0);
  STAGE(bSrc1, 5, 0);
  STAGE(aSrc0, 0, 0);
  STAGE(aSrc1, 1, 0);
  STAGE(bSrc0, 6, 128);
  asm volatile("s_waitcnt vmcnt(2)" ::: "memory");
  BARRIER();

  i32x4 bq[4][2], av0[2][2], av1[2][2];
  RD_B(bSp0);
  RD_A(av0, aSp0, 0);

  for (int i = 0; i < NI; ++i) {
    const int t0 = 2 * i;
    const int k1 = (t0 + 1) * 128, k2 = (t0 + 2) * 128, k3 = (t0 + 3) * 128;

    // ---- Ph0: issue A q1; stage B1(t0+1)->s7; MFMA q0 ----
    RD_A(av1, aSp0, 1);
    STAGE(bSrc1, 7, k1);
    BARRIER();
    QMFMA(av0, 0);

    // ---- Ph1: issue A q2; stage A0(t0+1)->s2; MFMA q1 ----
    RD_A(av0, aSp0, 2);
    STAGE(aSrc0, 2, k1);
    BARRIER();
    QMFMA(av1, 1);

    // ---- Ph2: issue A q3; stage A1(t0+1)->s3; MFMA q2 ----
    RD_A(av1, aSp0, 3);
    STAGE(aSrc1, 3, k1);
    BARRIER();
    QMFMA(av0, 2);

    // ---- Ph3: stage B0(t0+2)->s4; GATE step t0+1; MFMA q3;
    //      then issue step t0+1's B + A q0 (post-barrier) ----
    if (t0 + 2 < NT) {
      STAGE(bSrc0, 4, k2);
      asm volatile("s_waitcnt vmcnt(2)" ::: "memory");
    } else {
      asm volatile("s_waitcnt vmcnt(0)" ::: "memory");
    }
    BARRIER();
    QMFMA(av1, 3);
    RD_B(bSp1);
    RD_A(av0, aSp1, 0);

    // ---- Ph4: issue A q1; stage B1(t0+2)->s5; MFMA q0 ----
    RD_A(av1, aSp1, 1);
    if (t0 + 2 < NT) STAGE(bSrc1, 5, k2);
    BARRIER();
    QMFMA(av0, 0);

    // ---- Ph5: issue A q2; stage A0(t0+2)->s0; MFMA q1 ----
    RD_A(av0, aSp1, 2);
    if (t0 + 2 < NT) STAGE(aSrc0, 0, k2);
    BARRIER();
    QMFMA(av1, 1);

    // ---- Ph6: issue A q3; stage A1(t0+2)->s1; MFMA q2 ----
    RD_A(av1, aSp1, 3);
    if (t0 + 2 < NT) STAGE(aSrc1, 1, k2);
    BARRIER();
    QMFMA(av0, 2);

    // ---- Ph7: stage B0(t0+3)->s6; GATE step t0+2; MFMA q3;
    //      then issue step t0+2's B + A q0 ----
    if (t0 + 2 < NT) {
      STAGE(bSrc0, 6, k3);
      asm volatile("s_waitcnt vmcnt(2)" ::: "memory");
    }
    BARRIER();
    QMFMA(av1, 3);
    if (t0 + 2 < NT) {
      RD_B(bSp0);
      RD_A(av0, aSp0, 0);
    }
  }

  // ---- epilogue: per-block scale reduce (fixed order, bit-identical
  //      across blocks), then C = scale_w * qrow[row] * acc ----
  BARRIER();  // all LDS reads of the K-loop drained block-wide
  float s = 0.f;
  for (int i = tid; i < 4096; i += 512) s += partials[i];  // 8 per thread
#pragma unroll
  for (int off = 32; off > 0; off >>= 1) s += __shfl_down(s, off, 64);
  float* smf = reinterpret_cast<float*>(lds);
  if (lane == 0) smf[wid] = s;
  BARRIER();
  float tot = 0.f;
#pragma unroll
  for (int j = 0; j < 8; ++j) tot += smf[j];
  const float sc = tot * (1.0f / 16777216.0f);

  const int crow0 = tm * 256 + wr * 128 + fq * 4;
  const int ccol0 = tn * 256 + wc * 64 + fr;
#pragma unroll
  for (int m = 0; m < 8; ++m) {
    const int row = crow0 + m * 16;
    float q[4];
#pragma unroll
    for (int j = 0; j < 4; ++j) q[j] = sc * qrow[row + j];
#pragma unroll
    for (int n = 0; n < 4; ++n) {
      i32x4 v = acc[m][n];
      float* cp = C + (size_t)row * N + ccol0 + n * 16;
#pragma unroll
      for (int j = 0; j < 4; ++j) cp[(size_t)j * N] = (float)v[j] * q[j];
    }
  }
#undef STAGE
#undef RD_A
#undef RD_B
#undef QMFMA
}

// ---- fused prep: blocks 0..8191 = xquant rows; 8192..12287 = wsign ------
__global__ __launch_bounds__(256) void prep_kernel(
    const float* __restrict__ X, const float* __restrict__ W,
    char* __restrict__ XQ, char* __restrict__ SQ,
    float* __restrict__ qrow, float* __restrict__ partials) {
  const int b = blockIdx.x;
  const int tid = threadIdx.x;
  if (b < 8192) {
    // ---- xquant: one row, per-row amax -> i8 ----
    const int row = b;
    const float4* xr =
        reinterpret_cast<const float4*>(X + (size_t)row * 4096);
    int* xo = reinterpret_cast<int*>(XQ + (size_t)row * 4096);
    float4 v[4];
    float am = 0.f;
#pragma unroll
    for (int i = 0; i < 4; ++i) {
      v[i] = xr[tid + 256 * i];
      am = fmaxf(am, fmaxf(fmaxf(fabsf(v[i].x), fabsf(v[i].y)),
                           fmaxf(fabsf(v[i].z), fabsf(v[i].w))));
    }
#pragma unroll
    for (int off = 1; off < 64; off <<= 1)
      am = fmaxf(am, __shfl_xor(am, off, 64));
    __shared__ float wm[4];
    if ((tid & 63) == 0) wm[tid >> 6] = am;
    __syncthreads();
    float amax = fmaxf(fmaxf(wm[0], wm[1]), fmaxf(wm[2], wm[3]));
    amax = fmaxf(amax, 1e-20f);
    const float rq = 127.f / amax;
#pragma unroll
    for (int i = 0; i < 4; ++i) {
      int b0 = __float2int_rn(v[i].x * rq);
      int b1 = __float2int_rn(v[i].y * rq);
      int b2 = __float2int_rn(v[i].z * rq);
      int b3 = __float2int_rn(v[i].w * rq);
      xo[tid + 256 * i] = (b0 & 255) | ((b1 & 255) << 8) |
                          ((b2 & 255) << 16) | ((b3 & 255) << 24);
    }
    if (tid == 0) qrow[row] = amax * (1.f / 127.f);
  } else {
    // ---- wsign: sign(W) -> i8, partial |W| sums ----
    const int base = (b - 8192) * 1024;
    const float4* wp = reinterpret_cast<const float4*>(W);
    int* sp = reinterpret_cast<int*>(SQ);
    float s = 0.f;
#pragma unroll
    for (int i = 0; i < 4; ++i) {
      const int idx = base + tid + 256 * i;
      float4 w = wp[idx];
      int b0 = (w.x > 0.f) - (w.x < 0.f);
      int b1 = (w.y > 0.f) - (w.y < 0.f);
      int b2 = (w.z > 0.f) - (w.z < 0.f);
      int b3 = (w.w > 0.f) - (w.w < 0.f);
      sp[idx] = (b0 & 255) | ((b1 & 255) << 8) | ((b2 & 255) << 16) |
                ((b3 & 255) << 24);
      s += fabsf(w.x) + fabsf(w.y) + fabsf(w.z) + fabsf(w.w);
    }
#pragma unroll
    for (int off = 32; off > 0; off >>= 1) s += __shfl_down(s, off, 64);
    __shared__ float sm[4];
    if ((tid & 63) == 0) sm[tid >> 6] = s;
    __syncthreads();
    if (tid == 0) partials[b - 8192] = sm[0] + sm[1] + sm[2] + sm[3];
  }
}

extern "C" void kernel_launch(void* const* d_in, const int* in_sizes, int n_in,
                              void* d_out, int out_size, void* d_ws,
                              size_t ws_size, hipStream_t stream) {
  const float* x = (const float*)d_in[0];   // [8192][4096] f32
  const float* w = (const float*)d_in[1];   // [4096][4096] f32
  float* out = (float*)d_out;               // [8192][4096] f32

  char* ws = (char*)d_ws;
  char* xq = ws;                                   // 32 MiB
  char* sq = ws + 33554432;                        // 16 MiB
  float* qrow = (float*)(ws + 50331648);           // 8192 f32
  float* partials = (float*)(ws + 50331648 + 32768);  // 4096 f32

  prep_kernel<<<12288, 256, 0, stream>>>(x, w, xq, sq, qrow, partials);
  gemm_i8_kernel<<<512, 512, 0, stream>>>(xq, sq, partials, qrow, out);
}